// Round 9
// baseline (340.889 us; speedup 1.0000x reference)
//
#include <hip/hip_runtime.h>
#include <hip/hip_bf16.h>

#define DIM_K 4096
#define DIM_N 4096
#define M_TOK 8192

typedef __attribute__((ext_vector_type(8))) short bf16x8;
typedef __attribute__((ext_vector_type(4))) float f32x4;

typedef const __attribute__((address_space(1))) unsigned int gu32;
typedef __attribute__((address_space(3))) unsigned int lu32;

__device__ __forceinline__ unsigned short f2bf(float f) {
  unsigned int u = __float_as_uint(f);
  u += 0x7FFFu + ((u >> 16) & 1u);   // round-to-nearest-even
  return (unsigned short)(u >> 16);
}

__device__ __forceinline__ void gload_lds16(const void* g, void* l) {
  __builtin_amdgcn_global_load_lds((gu32*)g, (lu32*)l, 16, 0, 0);
}

// ---------------- pre-pass 1: x fp32 [M][K] -> bf16 [M][K] ----------------
__global__ void cvt_x_kernel(const float* __restrict__ x,
                             unsigned short* __restrict__ xb, int n4) {
  int idx = blockIdx.x * blockDim.x + threadIdx.x;
  int stride = gridDim.x * blockDim.x;
  for (int i = idx; i < n4; i += stride) {
    float4 v = reinterpret_cast<const float4*>(x)[i];
    ushort4 o;
    o.x = f2bf(v.x); o.y = f2bf(v.y); o.z = f2bf(v.z); o.w = f2bf(v.w);
    reinterpret_cast<ushort4*>(xb)[i] = o;
  }
}

// ---------- pre-pass 2: W fp32 [K][N] -> Wt bf16 [N][K] (transpose) --------
__global__ void cvt_wt_kernel(const float* __restrict__ W,
                              unsigned short* __restrict__ Wt) {
  __shared__ unsigned short tile[32][33];
  const int k0 = blockIdx.x * 32;
  const int n0 = blockIdx.y * 32;
  const int kendn = (n0 < 1024) ? 1024 : (n0 < 2048 ? 2048 : 4096);
  if (k0 >= kendn) return;
  const int tx = threadIdx.x;  // 0..31
  const int ty = threadIdx.y;  // 0..7
#pragma unroll
  for (int j = 0; j < 4; ++j) {
    int k = k0 + ty + 8 * j;
    tile[ty + 8 * j][tx] = f2bf(W[(size_t)k * DIM_N + n0 + tx]);
  }
  __syncthreads();
#pragma unroll
  for (int j = 0; j < 4; ++j) {
    int n = n0 + ty + 8 * j;
    Wt[(size_t)n * DIM_K + k0 + tx] = tile[tx][ty + 8 * j];
  }
}

// ---------------------------------------------------------------------------
// 256x256 GEMM, C = A * Bt^T, bf16 MFMA 16x16x32. R4's proven ring schedule,
// with B OPERANDS LOADED DIRECTLY GLOBAL->REGISTERS (no B in LDS):
//  - LDS holds A only: 4-deep ring of 16KB K-tiles (64KB total) => 2 blocks/CU.
//  - per K-tile LDS traffic: 64KB read + 16KB write (~950 cyc) < matrix pipe
//    (1242 cyc) => matrix-bound, vs R4's 96+32KB (~sum-bound at 2268 cyc).
//  - B loads are VGPR-target: zero cross-wave hazards, compiler-counted waits.
//  - B panels are L2-resident via XCD-binding swizzle: n-tile = f(bid%8), so
//    each XCD reads ONE B panel (2MB heavy / 1MB mid / 0.5MB light) < 4MB L2.
// Ring safety (unchanged from R4, verified): reads of buf[(k+1)&3] in iter k;
// STAGE at iter k targets buf[(k+3)&3]; vmcnt(6)/iter (4 B-loads + 2 A-stages
// issued per iter) drains iter k-1's stages => stage(k+2) resident before
// iter k+1 reads it; WAR distance >= 2 barriers.
// ---------------------------------------------------------------------------
__global__ __launch_bounds__(512, 2) void gemm_kernel(
    const unsigned short* __restrict__ A,   // [M][K] bf16
    const unsigned short* __restrict__ Bt,  // [N][K] bf16
    float* __restrict__ C) {
  __shared__ unsigned short lds[32768];  // 64 KB: 4 bufs x (256 rows x 32 k)

  const int tid = threadIdx.x;
  const int lane = tid & 63;
  const int w = tid >> 6;   // 0..7
  const int wr = w >> 2;    // 0..1 : M half (128 rows)
  const int wc = w & 3;     // 0..3 : N quarter (64 cols)

  // XCD-binding block swizzle: heavy tiles (kend=4096) first, and each XCD
  // (bid%8, round-robin dispatch) works a single n-panel at a time.
  const int bid = blockIdx.x;
  int bx, by;
  if (bid < 256)      { by = 8 + (bid & 7);          bx = bid >> 3; }
  else if (bid < 384) { int t = bid - 256; by = 4 + (t & 3); bx = t >> 2; }
  else                { int t = bid - 384; by = t & 3;       bx = t >> 2; }
  const int m0 = bx * 256;
  const int n0 = by * 256;
  const int kend = (n0 < 1024) ? 1024 : (n0 < 2048 ? 2048 : 4096);
  const int nk = kend >> 5;          // K-tiles of 32: 32 / 64 / 128

  const unsigned short* Ab = A + (size_t)m0 * DIM_K;

  // --- A staging geometry (proven R4): linear LDS dest, inverse-swizzled
  //     global source. slot_k = k ^ (((row>>1)&3)<<3) in element space.
  int srcoff[2];
#pragma unroll
  for (int i = 0; i < 2; ++i) {
    int L = i * 8192 + w * 1024 + lane * 16;   // byte offset in 16KB tile
    int r = L >> 6;                            // row (64B rows)
    int kc = (L >> 4) & 3;
    int ks = (kc ^ ((r >> 1) & 3)) << 3;
    srcoff[i] = r * DIM_K + ks;
  }
  const int dstoff0 = w * 512;           // shorts, wave-uniform
  const int dstoff1 = 4096 + w * 512;

  // --- fragment geometry (16x16x32: row/col = lane&15, k=(lane>>4)*8+j)
  const int l15 = lane & 15;
  const int kb = (lane >> 4) << 3;
  const int rA = wr * 128 + l15;
  const int koffA = kb ^ (((rA >> 1) & 3) << 3);

  // B global base for this thread: row n0 + wc*64 + l15 (+ni*16), col kb
  const unsigned short* Bb2 = Bt + (size_t)(n0 + wc * 64 + l15) * DIM_K + kb;

#define AFRAG(bufc, mi) \
  (*reinterpret_cast<const bf16x8*>(&lds[(bufc)*8192 + (rA + (mi)*16)*32 + koffA]))

#define STAGE(kt, bufc)                                                        \
  do {                                                                         \
    gload_lds16(Ab + (size_t)(kt) * 32 + srcoff[0], &lds[(bufc)*8192 + dstoff0]); \
    gload_lds16(Ab + (size_t)(kt) * 32 + srcoff[1], &lds[(bufc)*8192 + dstoff1]); \
  } while (0)

#define READA(Af, bufc)                                                        \
  { _Pragma("unroll") for (int mi = 0; mi < 8; ++mi) Af[mi] = AFRAG(bufc, mi); }

#define LOADB(Bf, kt)                                                          \
  { _Pragma("unroll") for (int ni = 0; ni < 4; ++ni)                           \
      Bf[ni] = *reinterpret_cast<const bf16x8*>(                               \
          Bb2 + (size_t)(ni * 16) * DIM_K + ((kt) << 5)); }

#define MFMA32(Af, Bf)                                                         \
  do {                                                                         \
    __builtin_amdgcn_s_setprio(1);                                             \
    _Pragma("unroll") for (int mi = 0; mi < 8; ++mi)                           \
      _Pragma("unroll") for (int ni = 0; ni < 4; ++ni)                         \
        acc[mi][ni] = __builtin_amdgcn_mfma_f32_16x16x32_bf16(                 \
            Af[mi], Bf[ni], acc[mi][ni], 0, 0, 0);                             \
    __builtin_amdgcn_s_setprio(0);                                             \
  } while (0)

  f32x4 acc[8][4];
#pragma unroll
  for (int i = 0; i < 8; ++i)
#pragma unroll
    for (int j = 0; j < 4; ++j) acc[i][j] = (f32x4){0.f, 0.f, 0.f, 0.f};

  bf16x8 A0[8], A1[8], B0[4], B1[4];

  // --- prologue: stage A tiles 0,1,2 ; load B tile 0 to regs
  STAGE(0, 0);
  STAGE(1, 1);
  STAGE(2, 2);
  LOADB(B0, 0);
  asm volatile("s_waitcnt vmcnt(8)" ::: "memory");  // A-stage(0) complete
  __builtin_amdgcn_s_barrier();
  READA(A0, 0);                                      // tile 0 A-frags

  // --- main loop: one barrier per K-tile; A ring 4-deep; B reg ping-pong
  for (int kk = 0; kk < nk; kk += 4) {
#pragma unroll
    for (int u = 0; u < 4; ++u) {
      const int k = kk + u;
      const int nxtbuf = (u + 1) & 3;          // (k+1)&3
      const int sbuf = (u + 3) & 3;
      const int kt = (k + 3 < nk) ? (k + 3) : (nk - 1);
      const int ktb = (k + 1 < nk) ? (k + 1) : (nk - 1);

      if ((u & 1) == 0) {
        READA(A1, nxtbuf);                     // A-frags for tile k+1
        LOADB(B1, ktb);                        // B-frags for tile k+1 (global)
        STAGE(kt, sbuf);
        MFMA32(A0, B0);                        // compute tile k
      } else {
        READA(A0, nxtbuf);
        LOADB(B0, ktb);
        STAGE(kt, sbuf);
        MFMA32(A1, B1);
      }
      asm volatile("s_waitcnt vmcnt(6)" ::: "memory");  // drain iter k-1 VM ops
      __builtin_amdgcn_s_barrier();
    }
  }

  // --- epilogue: C/D layout col=lane&15, row=(lane>>4)*4+reg
  const int crow0 = m0 + wr * 128 + (lane >> 4) * 4;
  const int ccol0 = n0 + wc * 64 + l15;
#pragma unroll
  for (int mi = 0; mi < 8; ++mi)
#pragma unroll
    for (int ni = 0; ni < 4; ++ni) {
      float* Cp = C + (size_t)(crow0 + mi * 16) * DIM_N + ccol0 + ni * 16;
#pragma unroll
      for (int r2 = 0; r2 < 4; ++r2) Cp[(size_t)r2 * DIM_N] = acc[mi][ni][r2];
    }
#undef AFRAG
#undef STAGE
#undef READA
#undef LOADB
#undef MFMA32
}

extern "C" void kernel_launch(void* const* d_in, const int* in_sizes, int n_in,
                              void* d_out, int out_size, void* d_ws,
                              size_t ws_size, hipStream_t stream) {
  const float* x = (const float*)d_in[0];
  const float* W = (const float*)d_in[1];
  float* out = (float*)d_out;

  unsigned short* xb = (unsigned short*)d_ws;                  // 64 MB
  unsigned short* wt = xb + (size_t)M_TOK * DIM_K;             // 32 MB

  cvt_x_kernel<<<2048, 256, 0, stream>>>(x, xb, M_TOK * DIM_K / 4);
  cvt_wt_kernel<<<dim3(DIM_K / 32, DIM_N / 32), dim3(32, 8), 0, stream>>>(W, wt);
  gemm_kernel<<<512, 512, 0, stream>>>(xb, wt, out);
}

// Round 11
// 247.490 us; speedup vs baseline: 1.3774x; 1.3774x over previous
//
#include <hip/hip_runtime.h>
#include <hip/hip_bf16.h>

#define DIM_K 4096
#define DIM_N 4096
#define M_TOK 8192

typedef __attribute__((ext_vector_type(8))) short bf16x8;
typedef __attribute__((ext_vector_type(4))) float f32x4;

typedef const __attribute__((address_space(1))) unsigned int gu32;
typedef __attribute__((address_space(3))) unsigned int lu32;

__device__ __forceinline__ unsigned short f2bf(float f) {
  unsigned int u = __float_as_uint(f);
  u += 0x7FFFu + ((u >> 16) & 1u);   // round-to-nearest-even
  return (unsigned short)(u >> 16);
}

__device__ __forceinline__ void gload_lds16(const void* g, void* l) {
  __builtin_amdgcn_global_load_lds((gu32*)g, (lu32*)l, 16, 0, 0);
}

// ---------------- pre-pass 1: x fp32 [M][K] -> bf16 [M][K] ----------------
__global__ void cvt_x_kernel(const float* __restrict__ x,
                             unsigned short* __restrict__ xb, int n4) {
  int idx = blockIdx.x * blockDim.x + threadIdx.x;
  int stride = gridDim.x * blockDim.x;
  for (int i = idx; i < n4; i += stride) {
    float4 v = reinterpret_cast<const float4*>(x)[i];
    ushort4 o;
    o.x = f2bf(v.x); o.y = f2bf(v.y); o.z = f2bf(v.z); o.w = f2bf(v.w);
    reinterpret_cast<ushort4*>(xb)[i] = o;
  }
}

// ---------- pre-pass 2: W fp32 [K][N] -> Wt bf16 [N][K] (transpose) --------
// Staircase-aware: blocks fully inside the zero region exit immediately.
__global__ void cvt_wt_kernel(const float* __restrict__ W,
                              unsigned short* __restrict__ Wt) {
  __shared__ unsigned short tile[32][33];
  const int k0 = blockIdx.x * 32;
  const int n0 = blockIdx.y * 32;
  const int kendn = (n0 < 1024) ? 1024 : (n0 < 2048 ? 2048 : 4096);
  if (k0 >= kendn) return;
  const int tx = threadIdx.x;  // 0..31
  const int ty = threadIdx.y;  // 0..7
#pragma unroll
  for (int j = 0; j < 4; ++j) {
    int k = k0 + ty + 8 * j;
    tile[ty + 8 * j][tx] = f2bf(W[(size_t)k * DIM_N + n0 + tx]);
  }
  __syncthreads();
#pragma unroll
  for (int j = 0; j < 4; ++j) {
    int n = n0 + ty + 8 * j;
    Wt[(size_t)n * DIM_K + k0 + tx] = tile[tx][ty + 8 * j];
  }
}

// ---------------------------------------------------------------------------
// 128x256-tile GEMM, C = A * Bt^T, bf16 MFMA 16x16x32.
// R4's PROVEN ring schedule (4-deep LDS ring, BK=32, stage lead 3, one
// barrier + counted vmcnt per K-tile, ping-pong frag regs, XOR swizzle),
// retiled 256x256 -> 128x256 for PERFECT round packing:
//   1024 blocks @ 1 block/CU = 4 rounds: {heavy, heavy, mid, light}
//   per-CU work = 128+128+64+32 = 352 = exact average (R4 had ~9% tail).
// Ring safety (R4's argument, incl. the SECOND PROLOGUE WAIT that R10
// dropped — its absence let iter 0 read buf1 before stage(1) landed -> NaN):
//   prologue: vmcnt(6)=stage(0) done; READF(tile0); vmcnt(3)=stage(1) done.
//   iter k trailing vmcnt(3) drains iter k-1's stage (tile k+2) before the
//   barrier => iter k+1's READF(tile k+2) is RAW-safe.
//   STAGE at iter k targets buf[(k+3)&3]=buf[(k-1)&3]; its ds_reads were
//   consumed by MFMA(k-1) before the k-1 barrier => WAR-safe.
// ---------------------------------------------------------------------------
__global__ __launch_bounds__(512, 2) void gemm_kernel(
    const unsigned short* __restrict__ A,   // [M][K] bf16
    const unsigned short* __restrict__ Bt,  // [N][K] bf16
    float* __restrict__ C) {
  __shared__ unsigned short lds[49152];  // 96 KB: 4 bufs x (A 8KB + B 16KB)

  const int tid = threadIdx.x;
  const int lane = tid & 63;
  const int w = tid >> 6;   // 0..7
  const int wr = w >> 2;    // 0..1 : M half (64 rows)
  const int wc = w & 3;     // 0..3 : N quarter (64 cols)

  // heavy n-panels (kend=4096) first => rounds pack perfectly.
  const int bid = blockIdx.x;
  int bx, by;
  if (bid < 512)      { by = 8 + (bid >> 6);               bx = bid & 63; }
  else if (bid < 768) { int t = bid - 512; by = 4 + (t >> 6); bx = t & 63; }
  else                { int t = bid - 768; by = t >> 6;       bx = t & 63; }
  const int m0 = bx * 128;
  const int n0 = by * 256;
  const int kend = (n0 < 1024) ? 1024 : (n0 < 2048 ? 2048 : 4096);
  const int nk = kend >> 5;          // K-tiles of 32: 32 / 64 / 128

  const unsigned short* Ab = A + (size_t)m0 * DIM_K;
  const unsigned short* Bb = Bt + (size_t)n0 * DIM_K;

  // --- staging geometry (R4 pattern): linear LDS dest, inverse-swizzled
  //     global source. slot_k = k ^ (((row>>1)&3)<<3) in element space.
  //     A: 1 load/thread covers 128 rows x 64B; B: 2 loads cover 256 rows.
  const int rr = w * 16 + (lane >> 2);            // 0..127
  const int ks0 = (((lane & 3) ^ ((rr >> 1) & 3)) << 3);
  const size_t srcA = (size_t)rr * DIM_K + ks0;   // A rows 0..127
  const size_t srcB0 = srcA;                      // B rows 0..127
  const size_t srcB1 = srcA + (size_t)128 * DIM_K;  // B rows 128..255 (same swz)
  const int dstw = w * 512;                       // shorts, wave-uniform

  // --- fragment geometry (16x16x32: row/col = lane&15, k=(lane>>4)*8+j)
  const int l15 = lane & 15;
  const int kb = (lane >> 4) << 3;
  const int rA = wr * 64 + l15;
  const int rB = wc * 64 + l15;
  const int koffA = kb ^ (((rA >> 1) & 3) << 3);
  const int koffB = kb ^ (((rB >> 1) & 3) << 3);

#define AFRAG(bufc, mi) (*reinterpret_cast<const bf16x8*>( \
    &lds[(bufc)*12288 + (rA + (mi)*16)*32 + koffA]))
#define BFRAG(bufc, ni) (*reinterpret_cast<const bf16x8*>( \
    &lds[(bufc)*12288 + 4096 + (rB + (ni)*16)*32 + koffB]))

#define STAGE(kt, bufc)                                                       \
  do {                                                                        \
    gload_lds16(Ab + ((size_t)(kt) << 5) + srcA,  &lds[(bufc)*12288 + dstw]); \
    gload_lds16(Bb + ((size_t)(kt) << 5) + srcB0, &lds[(bufc)*12288 + 4096 + dstw]); \
    gload_lds16(Bb + ((size_t)(kt) << 5) + srcB1, &lds[(bufc)*12288 + 8192 + dstw]); \
  } while (0)

#define READF(Af, Bf, bufc)                                                   \
  do {                                                                        \
    _Pragma("unroll") for (int mi = 0; mi < 4; ++mi) Af[mi] = AFRAG(bufc, mi);\
    _Pragma("unroll") for (int ni = 0; ni < 4; ++ni) Bf[ni] = BFRAG(bufc, ni);\
  } while (0)

#define MFMA16(Af, Bf)                                                        \
  do {                                                                        \
    __builtin_amdgcn_s_setprio(1);                                            \
    _Pragma("unroll") for (int mi = 0; mi < 4; ++mi)                          \
      _Pragma("unroll") for (int ni = 0; ni < 4; ++ni)                        \
        acc[mi][ni] = __builtin_amdgcn_mfma_f32_16x16x32_bf16(                \
            Af[mi], Bf[ni], acc[mi][ni], 0, 0, 0);                            \
    __builtin_amdgcn_s_setprio(0);                                            \
  } while (0)

  f32x4 acc[4][4];
#pragma unroll
  for (int i = 0; i < 4; ++i)
#pragma unroll
    for (int j = 0; j < 4; ++j) acc[i][j] = (f32x4){0.f, 0.f, 0.f, 0.f};

  bf16x8 A0[4], A1[4], B0[4], B1[4];

  // --- prologue: stage tiles 0,1,2 (9 loads)
  STAGE(0, 0);
  STAGE(1, 1);
  STAGE(2, 2);
  asm volatile("s_waitcnt vmcnt(6)" ::: "memory");  // stage(0) complete
  __builtin_amdgcn_s_barrier();
  READF(A0, B0, 0);                                  // tile 0 frags
  asm volatile("s_waitcnt vmcnt(3)" ::: "memory");  // stage(1) complete
  __builtin_amdgcn_s_barrier();

  // --- main loop: one barrier per K-tile, ping-pong frag regs (static idx)
  for (int kk = 0; kk < nk; kk += 4) {
#pragma unroll
    for (int u = 0; u < 4; ++u) {
      const int k = kk + u;
      const int nxtbuf = (u + 1) & 3;          // (k+1)&3
      const int sbuf = (u + 3) & 3;
      const int kt = (k + 3 < nk) ? (k + 3) : (nk - 1);

      if ((u & 1) == 0) {
        READF(A1, B1, nxtbuf);                 // frags for tile k+1
        STAGE(kt, sbuf);
        MFMA16(A0, B0);                        // compute tile k
      } else {
        READF(A0, B0, nxtbuf);
        STAGE(kt, sbuf);
        MFMA16(A1, B1);
      }
      asm volatile("s_waitcnt vmcnt(3)" ::: "memory");  // iter k-1 stages done
      __builtin_amdgcn_s_barrier();
    }
  }

  // --- epilogue: C/D layout col=lane&15, row=(lane>>4)*4+reg
  const int crow0 = m0 + wr * 64 + (lane >> 4) * 4;
  const int ccol0 = n0 + wc * 64 + l15;
#pragma unroll
  for (int mi = 0; mi < 4; ++mi)
#pragma unroll
    for (int ni = 0; ni < 4; ++ni) {
      float* Cp = C + (size_t)(crow0 + mi * 16) * DIM_N + ccol0 + ni * 16;
#pragma unroll
      for (int r2 = 0; r2 < 4; ++r2) Cp[(size_t)r2 * DIM_N] = acc[mi][ni][r2];
    }
#undef AFRAG
#undef BFRAG
#undef STAGE
#undef READF
#undef MFMA16
}

extern "C" void kernel_launch(void* const* d_in, const int* in_sizes, int n_in,
                              void* d_out, int out_size, void* d_ws,
                              size_t ws_size, hipStream_t stream) {
  const float* x = (const float*)d_in[0];
  const float* W = (const float*)d_in[1];
  float* out = (float*)d_out;

  unsigned short* xb = (unsigned short*)d_ws;                  // 64 MB
  unsigned short* wt = xb + (size_t)M_TOK * DIM_K;             // 32 MB

  cvt_x_kernel<<<2048, 256, 0, stream>>>(x, xb, M_TOK * DIM_K / 4);
  cvt_wt_kernel<<<dim3(DIM_K / 32, DIM_N / 32), dim3(32, 8), 0, stream>>>(W, wt);
  gemm_kernel<<<1024, 512, 0, stream>>>(xb, wt, out);
}